// Round 5
// baseline (555.350 us; speedup 1.0000x reference)
//
#include <hip/hip_runtime.h>

// TemporalTransformerConv on MI355X.
// Algebraic collapse: node/edge GEMMs fold into attn vectors since the
// message value el_prime is scalar-per-head.
// R5-R8: drop the CSR/bucket machinery entirely. After the collapse each
// edge contributes only 4 scalars (m0, m1, x0, x1) to its dst node, so
// direct fp32 atomic accumulation is 3.2M fire-and-forget RMWs into an
// 800KB L2-resident accumulator -- 4x fewer RMWs than the 12.8M that
// originally motivated the bucket design, and it eliminates:
//   - count pass (dst re-read + 0.8M int atomics)
//   - scan1 + scan23 launches
//   - 0.8M cursor atomics
//   - 12.8MB scattered bucket write (~4x line-amplified) + 12.8MB re-read
// Pipeline: 6 kernels -> 4. If this lands neutral, the kernel side is at
// its traffic floor (edge_raw 320MB stream) and the residual is the fixed
// harness overhead (1.28GB ws poison ~195us + ~322MB input restore).
// R8: identical resubmit (R6 compile-fix; R7/R8 runs died to container
// infra failures, not kernel issues).

constexpr int F = 100;           // NODE_F == EDGE_F == TIME_D == OUT_F
constexpr float NEG_SLOPE = 0.2f;
constexpr int EPB = 32;          // edges per block in edge_gemv_kernel

__device__ __forceinline__ float wave_reduce(float v) {
#pragma unroll
    for (int off = 32; off > 0; off >>= 1)
        v += __shfl_down(v, off, 64);
    return v;
}

// K0: fold fc_* weights through attn vectors. Also zeros accum[4N]
// (grid-stride) so the edge kernel can atomically accumulate into it.
__global__ void precompute_kernel(
    const float* __restrict__ fc_node_w, const float* __restrict__ fc_node_b,
    const float* __restrict__ fc_edge_w, const float* __restrict__ fc_edge_b,
    const float* __restrict__ attn_l, const float* __restrict__ attn_r,
    const float* __restrict__ attn_e,
    float4* __restrict__ w_node, float2* __restrict__ w_edge,
    float* __restrict__ bias,
    float* __restrict__ accum, int N)
{
    int wid  = blockIdx.x * (blockDim.x >> 6) + (threadIdx.x >> 6);
    int lane = threadIdx.x & 63;
    if (wid < F) {
        int t = wid;
        float a0 = 0.f, a1 = 0.f, a2 = 0.f, a3 = 0.f;
        for (int f = lane; f < F; f += 64) {
            float w0 = fc_node_w[t * 2 * F + f];
            float w1 = fc_node_w[t * 2 * F + F + f];
            a0 += w0 * attn_l[f];
            a1 += w1 * attn_l[F + f];
            a2 += w0 * attn_r[f];
            a3 += w1 * attn_r[F + f];
        }
        a0 = wave_reduce(a0); a1 = wave_reduce(a1);
        a2 = wave_reduce(a2); a3 = wave_reduce(a3);
        if (lane == 0) w_node[t] = make_float4(a0, a1, a2, a3);
    } else if (wid < 3 * F) {
        int t = wid - F;
        float a0 = 0.f, a1 = 0.f;
        for (int f = lane; f < F; f += 64) {
            a0 += fc_edge_w[t * 2 * F + f] * attn_e[f];
            a1 += fc_edge_w[t * 2 * F + F + f] * attn_e[F + f];
        }
        a0 = wave_reduce(a0); a1 = wave_reduce(a1);
        if (lane == 0) w_edge[t] = make_float2(a0, a1);
    } else if (wid < 3 * F + 6) {
        int j = wid - 3 * F;
        const float* b  = (j < 4) ? fc_node_b : fc_edge_b;
        const float* av = (j < 2) ? attn_l : (j < 4 ? attn_r : attn_e);
        int h = j & 1;
        float a0 = 0.f;
        for (int f = lane; f < F; f += 64)
            a0 += b[h * F + f] * av[h * F + f];
        a0 = wave_reduce(a0);
        if (lane == 0) bias[j] = a0;
    }
    // zero the per-node accumulator [N x 4] for the edge kernel
    int total = 4 * N;
    for (int i = blockIdx.x * blockDim.x + threadIdx.x; i < total;
         i += gridDim.x * blockDim.x)
        accum[i] = 0.f;
}

// K1: one wave per node: el/er.
__global__ void node_kernel(const float* __restrict__ memory,
                            const float4* __restrict__ w_node,
                            const float* __restrict__ bias,
                            float4* __restrict__ el_er, int N)
{
    int n    = blockIdx.x * (blockDim.x >> 6) + (threadIdx.x >> 6);
    int lane = threadIdx.x & 63;
    if (n >= N) return;
    const float* mrow = memory + (size_t)n * F;
    float a0 = 0.f, a1 = 0.f, a2 = 0.f, a3 = 0.f;
    for (int k = lane; k < F; k += 64) {
        float m  = mrow[k];
        float4 w = w_node[k];
        a0 += m * w.x; a1 += m * w.y; a2 += m * w.z; a3 += m * w.w;
    }
    a0 = wave_reduce(a0); a1 = wave_reduce(a1);
    a2 = wave_reduce(a2); a3 = wave_reduce(a3);
    if (lane == 0)
        el_er[n] = make_float4(a0 + bias[0], a1 + bias[1],
                               a2 + bias[2], a3 + bias[3]);
}

// K2: streaming edge GEMV. Edge rows read directly from HBM as float4
// (8 threads/edge). Weights in LDS as SoA float4[25] (broadcast reads).
// Leader accumulates (m0, m1, x0, x1) into accum[dst] with 4 fire-and-
// forget fp32 atomics (no return value -> global_atomic_add_f32).
__global__ void edge_gemv_kernel(
    const float* __restrict__ edge_raw,
    const float* __restrict__ edge_ts,
    const float* __restrict__ node_ts,
    const int* __restrict__ src,
    const int* __restrict__ dst,
    const float* __restrict__ time_w,
    const float* __restrict__ time_b,
    const float2* __restrict__ w_edge,
    const float* __restrict__ bias,
    const float4* __restrict__ el_er,
    float* __restrict__ accum, int E)
{
    __shared__ float4 wx4[25], wy4[25], wz4[25], ww4[25], tw4[25], tb4[25];
    __shared__ float  td_s[EPB];
    __shared__ float2 el_s[EPB];
    __shared__ float2 er_s[EPB];
    __shared__ int    d_s[EPB];

    const int  t  = threadIdx.x;
    const long eb = (long)blockIdx.x * EPB;

    if (t < 25) {
        float4 x, y, z, w, tw, tb;
#pragma unroll
        for (int j = 0; j < 4; ++j) {
            int k = 4 * t + j;
            float2 wr = w_edge[k];
            float2 wt = w_edge[F + k];
            ((float*)&x)[j]  = wr.x;  ((float*)&y)[j]  = wr.y;
            ((float*)&z)[j]  = wt.x;  ((float*)&w)[j]  = wt.y;
            ((float*)&tw)[j] = time_w[k];
            ((float*)&tb)[j] = time_b[k];
        }
        wx4[t] = x; wy4[t] = y; wz4[t] = z; ww4[t] = w;
        tw4[t] = tw; tb4[t] = tb;
    } else if (t >= 64 && t < 64 + EPB) {
        int  l = t - 64;
        long e = eb + l;
        if (e < E) {
            int s = src[e], d = dst[e];
            d_s[l]  = d;
            td_s[l] = edge_ts[e] - node_ts[s];
            float4 a = el_er[s];
            float4 b = el_er[d];
            el_s[l] = make_float2(a.x, a.y);
            er_s[l] = make_float2(b.z, b.w);
        }
    }
    __syncthreads();

    const int  el_ = t >> 3;      // local edge 0..31
    const int  s8  = t & 7;       // slot within edge
    const long e   = eb + el_;
    float a0 = 0.f, a1 = 0.f;
    if (e < E) {
        const float  td   = td_s[el_];
        const float4* row = (const float4*)edge_raw + e * 25;
#pragma unroll
        for (int i = 0; i < 4; ++i) {
            int c = s8 + 8 * i;
            if (c < 25) {
                float4 r  = row[c];
                float4 x  = wx4[c], y = wy4[c], z = wz4[c], w = ww4[c];
                float4 tw = tw4[c], tb = tb4[c];
                float c0 = __cosf(fmaf(td, tw.x, tb.x));
                float c1 = __cosf(fmaf(td, tw.y, tb.y));
                float c2 = __cosf(fmaf(td, tw.z, tb.z));
                float c3 = __cosf(fmaf(td, tw.w, tb.w));
                a0 = fmaf(r.x, x.x, fmaf(c0, z.x, a0));
                a1 = fmaf(r.x, y.x, fmaf(c0, w.x, a1));
                a0 = fmaf(r.y, x.y, fmaf(c1, z.y, a0));
                a1 = fmaf(r.y, y.y, fmaf(c1, w.y, a1));
                a0 = fmaf(r.z, x.z, fmaf(c2, z.z, a0));
                a1 = fmaf(r.z, y.z, fmaf(c2, w.z, a1));
                a0 = fmaf(r.w, x.w, fmaf(c3, z.w, a0));
                a1 = fmaf(r.w, y.w, fmaf(c3, w.w, a1));
            }
        }
    }
    a0 += __shfl_down(a0, 4, 64);  a1 += __shfl_down(a1, 4, 64);
    a0 += __shfl_down(a0, 2, 64);  a1 += __shfl_down(a1, 2, 64);
    a0 += __shfl_down(a0, 1, 64);  a1 += __shfl_down(a1, 1, 64);

    if (s8 == 0 && e < E) {
        float elp0 = el_s[el_].x + a0 + bias[4];
        float elp1 = el_s[el_].y + a1 + bias[5];
        float e0 = elp0 + er_s[el_].x;
        float e1 = elp1 + er_s[el_].y;
        e0 = e0 > 0.f ? e0 : NEG_SLOPE * e0;
        e1 = e1 > 0.f ? e1 : NEG_SLOPE * e1;
        float x0 = __expf(e0);
        float x1 = __expf(e1);
        float* acc = accum + 4 * (size_t)d_s[el_];
        atomicAdd(acc + 0, x0 * elp0);
        atomicAdd(acc + 1, x1 * elp1);
        atomicAdd(acc + 2, x0);
        atomicAdd(acc + 3, x1);
    }
}

// K3: 16 lanes per node: read accum[n] (same-address broadcast), compute
// the scalar head-mean, write the 100-float row out[n,:] = memory[n,:]+add.
__global__ void out_kernel(const float4* __restrict__ accum,
                           const float* __restrict__ memory,
                           float* __restrict__ out, int N)
{
    int g = blockIdx.x * (blockDim.x >> 4) + (threadIdx.x >> 4);  // node
    int l = threadIdx.x & 15;
    if (g >= N) return;
    float4 a = accum[g];
    float ft0 = (a.z != 0.f) ? a.x / a.z : 0.f;
    float ft1 = (a.w != 0.f) ? a.y / a.w : 0.f;
    float add = 0.5f * (ft0 + ft1);

    const float4* m4 = (const float4*)(memory + (size_t)g * F);
    float4*       o4 = (float4*)(out + (size_t)g * F);
#pragma unroll
    for (int c = l; c < F / 4; c += 16) {   // 25 float4 per row
        float4 m = m4[c];
        float4 o;
        o.x = m.x + add; o.y = m.y + add;
        o.z = m.z + add; o.w = m.w + add;
        o4[c] = o;
    }
}

extern "C" void kernel_launch(void* const* d_in, const int* in_sizes, int n_in,
                              void* d_out, int out_size, void* d_ws, size_t ws_size,
                              hipStream_t stream)
{
    const float* memory     = (const float*)d_in[0];
    const float* node_ts    = (const float*)d_in[1];
    const float* edge_raw   = (const float*)d_in[2];
    const float* edge_ts    = (const float*)d_in[3];
    const float* time_w     = (const float*)d_in[4];
    const float* time_b     = (const float*)d_in[5];
    const float* fc_node_w  = (const float*)d_in[6];
    const float* fc_node_b  = (const float*)d_in[7];
    const float* fc_edge_w  = (const float*)d_in[8];
    const float* fc_edge_b  = (const float*)d_in[9];
    const float* attn_l     = (const float*)d_in[10];
    const float* attn_r     = (const float*)d_in[11];
    const float* attn_e     = (const float*)d_in[12];
    const int*   src        = (const int*)d_in[13];
    const int*   dst        = (const int*)d_in[14];
    float*       out        = (float*)d_out;

    const int N = in_sizes[1];   // node_ts
    const int E = in_sizes[3];   // edge_ts

    // workspace layout (floats):
    // [0,400)        w_node (100 x float4)
    // [400,800)      w_edge (200 x float2)
    // [800,816)      bias
    // [816,+4N)      el_er  (N x float4)
    // [.. ,+4N)      accum  (N x float4)
    float* ws = (float*)d_ws;
    float4* w_node  = (float4*)ws;
    float2* w_edge  = (float2*)(ws + 400);
    float*  bias    = ws + 800;
    float4* el_er   = (float4*)(ws + 816);
    float*  accum   = ws + 816 + 4 * (size_t)N;

    {
        int wblocks = (3 * F + 6 + 3) / 4;            // wave work
        int zblocks = (4 * N + 255) / 256;            // accum zeroing breadth
        int blocks  = (zblocks > wblocks) ? zblocks : wblocks;
        precompute_kernel<<<blocks, 256, 0, stream>>>(
            fc_node_w, fc_node_b, fc_edge_w, fc_edge_b,
            attn_l, attn_r, attn_e, w_node, w_edge, bias, accum, N);
    }
    {
        int blocks = (N + 3) / 4;
        node_kernel<<<blocks, 256, 0, stream>>>(
            memory, w_node, bias, el_er, N);
    }
    {
        int blocks = (E + EPB - 1) / EPB;
        edge_gemv_kernel<<<blocks, 256, 0, stream>>>(
            edge_raw, edge_ts, node_ts, src, dst, time_w, time_b,
            w_edge, bias, el_er, accum, E);
    }
    {
        int blocks = (N + 15) / 16;
        out_kernel<<<blocks, 256, 0, stream>>>(
            (const float4*)accum, memory, out, N);
    }
}

// Round 6
// 547.085 us; speedup vs baseline: 1.0151x; 1.0151x over previous
//
#include <hip/hip_runtime.h>

// TemporalTransformerConv on MI355X.
// Algebraic collapse: node/edge GEMMs fold into attn vectors since the
// message value el_prime is scalar-per-head. Edge aggregation via on-the-fly
// CSR bucketing (int cursor atomics + plain float4 stores).
// R9: revert to the R4 design (best measured: 547.6us). The R5-R8
// experiment replaced CSR bucketing with 3.2M direct fp32 atomics and
// measured 555.3us -> atomics are rate-bound at >= the cost of the full
// CSR machinery. Both aggregation designs land within 1.4%; the total is
// dominated by fixed harness overhead (1.28GB poison fill ~192us + ~322MB
// input restore ~230us) plus the irreducible 320MB edge_raw stream.

constexpr int F = 100;           // NODE_F == EDGE_F == TIME_D == OUT_F
constexpr float NEG_SLOPE = 0.2f;
constexpr int EPB = 32;          // edges per block in edge_gemv_kernel

__device__ __forceinline__ float wave_reduce(float v) {
#pragma unroll
    for (int off = 32; off > 0; off >>= 1)
        v += __shfl_down(v, off, 64);
    return v;
}

// K0: fold fc_* weights through attn vectors. Also zeros cnt[] (grid-stride)
// so node and count can run fused in the next launch.
__global__ void precompute_kernel(
    const float* __restrict__ fc_node_w, const float* __restrict__ fc_node_b,
    const float* __restrict__ fc_edge_w, const float* __restrict__ fc_edge_b,
    const float* __restrict__ attn_l, const float* __restrict__ attn_r,
    const float* __restrict__ attn_e,
    float4* __restrict__ w_node, float2* __restrict__ w_edge,
    float* __restrict__ bias,
    int* __restrict__ cnt, int N)
{
    int wid  = blockIdx.x * (blockDim.x >> 6) + (threadIdx.x >> 6);
    int lane = threadIdx.x & 63;
    if (wid < F) {
        int t = wid;
        float a0 = 0.f, a1 = 0.f, a2 = 0.f, a3 = 0.f;
        for (int f = lane; f < F; f += 64) {
            float w0 = fc_node_w[t * 2 * F + f];
            float w1 = fc_node_w[t * 2 * F + F + f];
            a0 += w0 * attn_l[f];
            a1 += w1 * attn_l[F + f];
            a2 += w0 * attn_r[f];
            a3 += w1 * attn_r[F + f];
        }
        a0 = wave_reduce(a0); a1 = wave_reduce(a1);
        a2 = wave_reduce(a2); a3 = wave_reduce(a3);
        if (lane == 0) w_node[t] = make_float4(a0, a1, a2, a3);
    } else if (wid < 3 * F) {
        int t = wid - F;
        float a0 = 0.f, a1 = 0.f;
        for (int f = lane; f < F; f += 64) {
            a0 += fc_edge_w[t * 2 * F + f] * attn_e[f];
            a1 += fc_edge_w[t * 2 * F + F + f] * attn_e[F + f];
        }
        a0 = wave_reduce(a0); a1 = wave_reduce(a1);
        if (lane == 0) w_edge[t] = make_float2(a0, a1);
    } else if (wid < 3 * F + 6) {
        int j = wid - 3 * F;
        const float* b  = (j < 4) ? fc_node_b : fc_edge_b;
        const float* av = (j < 2) ? attn_l : (j < 4 ? attn_r : attn_e);
        int h = j & 1;
        float a0 = 0.f;
        for (int f = lane; f < F; f += 64)
            a0 += b[h * F + f] * av[h * F + f];
        a0 = wave_reduce(a0);
        if (lane == 0) bias[j] = a0;
    }
    // zero the in-degree histogram for the fused node+count launch
    for (int i = blockIdx.x * blockDim.x + threadIdx.x; i < N;
         i += gridDim.x * blockDim.x)
        cnt[i] = 0;
}

// K1 (fused): blocks [0, nodeBlocks) -> one wave per node computing el/er;
// blocks [nodeBlocks, ..) -> in-degree histogram over edges. Independent
// work, overlapped in one dispatch.
__global__ void node_count_kernel(const float* __restrict__ memory,
                                  const float4* __restrict__ w_node,
                                  const float* __restrict__ bias,
                                  float4* __restrict__ el_er,
                                  const int* __restrict__ dst,
                                  int* __restrict__ cnt,
                                  int N, int E, int nodeBlocks)
{
    if ((int)blockIdx.x < nodeBlocks) {
        int n    = blockIdx.x * (blockDim.x >> 6) + (threadIdx.x >> 6);
        int lane = threadIdx.x & 63;
        if (n >= N) return;
        const float* mrow = memory + (size_t)n * F;
        float a0 = 0.f, a1 = 0.f, a2 = 0.f, a3 = 0.f;
        for (int k = lane; k < F; k += 64) {
            float m  = mrow[k];
            float4 w = w_node[k];
            a0 += m * w.x; a1 += m * w.y; a2 += m * w.z; a3 += m * w.w;
        }
        a0 = wave_reduce(a0); a1 = wave_reduce(a1);
        a2 = wave_reduce(a2); a3 = wave_reduce(a3);
        if (lane == 0)
            el_er[n] = make_float4(a0 + bias[0], a1 + bias[1],
                                   a2 + bias[2], a3 + bias[3]);
    } else {
        int i = (blockIdx.x - nodeBlocks) * blockDim.x + threadIdx.x;
        if (i < E) atomicAdd(&cnt[dst[i]], 1);
    }
}

// CSR step 2a: per-block exclusive scan (Hillis-Steele in LDS).
__global__ void scan1_kernel(const int* __restrict__ cnt,
                             int* __restrict__ offs,
                             int* __restrict__ bsum, int N)
{
    __shared__ int tmp[256];
    int i = blockIdx.x * 256 + threadIdx.x;
    int v = (i < N) ? cnt[i] : 0;
    tmp[threadIdx.x] = v;
    __syncthreads();
    for (int d = 1; d < 256; d <<= 1) {
        int t = (threadIdx.x >= d) ? tmp[threadIdx.x - d] : 0;
        __syncthreads();
        tmp[threadIdx.x] += t;
        __syncthreads();
    }
    if (i < N) offs[i] = tmp[threadIdx.x] - v;    // exclusive
    if (threadIdx.x == 255) bsum[blockIdx.x] = tmp[255];
}

// CSR step 2b+2c fused: every block scans the (<=256) raw block sums in LDS
// itself, takes its own exclusive offset, and finalizes offs + cursor.
__global__ void scan23_kernel(int* __restrict__ offs,
                              const int* __restrict__ bsum,
                              int* __restrict__ cursor, int N, int nb)
{
    __shared__ int tmp[256];
    int t = threadIdx.x;
    int v = (t < nb) ? bsum[t] : 0;
    tmp[t] = v;
    __syncthreads();
    for (int d = 1; d < 256; d <<= 1) {
        int x = (t >= d) ? tmp[t - d] : 0;
        __syncthreads();
        tmp[t] += x;                    // inclusive scan of block sums
        __syncthreads();
    }
    int boff = (blockIdx.x == 0) ? 0 : tmp[blockIdx.x - 1];
    int i = blockIdx.x * 256 + t;
    if (i < N) {
        int o = offs[i] + boff;
        offs[i]   = o;
        cursor[i] = o;
    }
}

// K2: streaming edge GEMV. Edge rows read directly from HBM as float4
// (8 threads/edge). Weights in LDS as SoA float4[25] (broadcast reads).
// Leader computes y = (x0*elp0, x1*elp1, x0, x1) and bucket-writes it at
// pos = cursor[dst]++ (one int atomic per edge, plain float4 store).
__global__ void edge_gemv_kernel(
    const float* __restrict__ edge_raw,
    const float* __restrict__ edge_ts,
    const float* __restrict__ node_ts,
    const int* __restrict__ src,
    const int* __restrict__ dst,
    const float* __restrict__ time_w,
    const float* __restrict__ time_b,
    const float2* __restrict__ w_edge,
    const float* __restrict__ bias,
    const float4* __restrict__ el_er,
    int* __restrict__ cursor,
    float4* __restrict__ bucket, int E)
{
    __shared__ float4 wx4[25], wy4[25], wz4[25], ww4[25], tw4[25], tb4[25];
    __shared__ float  td_s[EPB];
    __shared__ float2 el_s[EPB];
    __shared__ float2 er_s[EPB];
    __shared__ int    d_s[EPB];

    const int  t  = threadIdx.x;
    const long eb = (long)blockIdx.x * EPB;

    if (t < 25) {
        float4 x, y, z, w, tw, tb;
#pragma unroll
        for (int j = 0; j < 4; ++j) {
            int k = 4 * t + j;
            float2 wr = w_edge[k];
            float2 wt = w_edge[F + k];
            ((float*)&x)[j]  = wr.x;  ((float*)&y)[j]  = wr.y;
            ((float*)&z)[j]  = wt.x;  ((float*)&w)[j]  = wt.y;
            ((float*)&tw)[j] = time_w[k];
            ((float*)&tb)[j] = time_b[k];
        }
        wx4[t] = x; wy4[t] = y; wz4[t] = z; ww4[t] = w;
        tw4[t] = tw; tb4[t] = tb;
    } else if (t >= 64 && t < 64 + EPB) {
        int  l = t - 64;
        long e = eb + l;
        if (e < E) {
            int s = src[e], d = dst[e];
            d_s[l]  = d;
            td_s[l] = edge_ts[e] - node_ts[s];
            float4 a = el_er[s];
            float4 b = el_er[d];
            el_s[l] = make_float2(a.x, a.y);
            er_s[l] = make_float2(b.z, b.w);
        }
    }
    __syncthreads();

    const int  el_ = t >> 3;      // local edge 0..31
    const int  s8  = t & 7;       // slot within edge
    const long e   = eb + el_;
    float a0 = 0.f, a1 = 0.f;
    if (e < E) {
        const float  td   = td_s[el_];
        const float4* row = (const float4*)edge_raw + e * 25;
#pragma unroll
        for (int i = 0; i < 4; ++i) {
            int c = s8 + 8 * i;
            if (c < 25) {
                float4 r  = row[c];
                float4 x  = wx4[c], y = wy4[c], z = wz4[c], w = ww4[c];
                float4 tw = tw4[c], tb = tb4[c];
                float c0 = __cosf(fmaf(td, tw.x, tb.x));
                float c1 = __cosf(fmaf(td, tw.y, tb.y));
                float c2 = __cosf(fmaf(td, tw.z, tb.z));
                float c3 = __cosf(fmaf(td, tw.w, tb.w));
                a0 = fmaf(r.x, x.x, fmaf(c0, z.x, a0));
                a1 = fmaf(r.x, y.x, fmaf(c0, w.x, a1));
                a0 = fmaf(r.y, x.y, fmaf(c1, z.y, a0));
                a1 = fmaf(r.y, y.y, fmaf(c1, w.y, a1));
                a0 = fmaf(r.z, x.z, fmaf(c2, z.z, a0));
                a1 = fmaf(r.z, y.z, fmaf(c2, w.z, a1));
                a0 = fmaf(r.w, x.w, fmaf(c3, z.w, a0));
                a1 = fmaf(r.w, y.w, fmaf(c3, w.w, a1));
            }
        }
    }
    a0 += __shfl_down(a0, 4, 64);  a1 += __shfl_down(a1, 4, 64);
    a0 += __shfl_down(a0, 2, 64);  a1 += __shfl_down(a1, 2, 64);
    a0 += __shfl_down(a0, 1, 64);  a1 += __shfl_down(a1, 1, 64);

    if (s8 == 0 && e < E) {
        float elp0 = el_s[el_].x + a0 + bias[4];
        float elp1 = el_s[el_].y + a1 + bias[5];
        float e0 = elp0 + er_s[el_].x;
        float e1 = elp1 + er_s[el_].y;
        e0 = e0 > 0.f ? e0 : NEG_SLOPE * e0;
        e1 = e1 > 0.f ? e1 : NEG_SLOPE * e1;
        float x0 = __expf(e0);
        float x1 = __expf(e1);
        int pos = atomicAdd(&cursor[d_s[el_]], 1);
        bucket[pos] = make_float4(x0 * elp0, x1 * elp1, x0, x1);
    }
}

// K3 (fused reduce+out): 16 lanes per node reduce the node's bucket slice
// (globally-sequential reads -> coalesced, no atomics), then the same 16
// lanes write the 100-float output row out[n,:] = memory[n,:] + add.
__global__ void reduce_out_kernel(const float4* __restrict__ bucket,
                                  const int* __restrict__ offs,
                                  const int* __restrict__ cnt,
                                  const float* __restrict__ memory,
                                  float* __restrict__ out, int N)
{
    int g = blockIdx.x * (blockDim.x >> 4) + (threadIdx.x >> 4);  // node
    int l = threadIdx.x & 15;
    if (g >= N) return;
    int base = offs[g];
    int deg  = cnt[g];
    float s0 = 0.f, s1 = 0.f, s2 = 0.f, s3 = 0.f;
    for (int j = l; j < deg; j += 16) {
        float4 v = bucket[base + j];
        s0 += v.x; s1 += v.y; s2 += v.z; s3 += v.w;
    }
    s0 += __shfl_down(s0, 8, 64); s1 += __shfl_down(s1, 8, 64);
    s2 += __shfl_down(s2, 8, 64); s3 += __shfl_down(s3, 8, 64);
    s0 += __shfl_down(s0, 4, 64); s1 += __shfl_down(s1, 4, 64);
    s2 += __shfl_down(s2, 4, 64); s3 += __shfl_down(s3, 4, 64);
    s0 += __shfl_down(s0, 2, 64); s1 += __shfl_down(s1, 2, 64);
    s2 += __shfl_down(s2, 2, 64); s3 += __shfl_down(s3, 2, 64);
    s0 += __shfl_down(s0, 1, 64); s1 += __shfl_down(s1, 1, 64);
    s2 += __shfl_down(s2, 1, 64); s3 += __shfl_down(s3, 1, 64);
    // lanes != 0 compute garbage here; only lane 0's value is broadcast
    float ft0 = (s2 != 0.f) ? s0 / s2 : 0.f;
    float ft1 = (s3 != 0.f) ? s1 / s3 : 0.f;
    float add = 0.5f * (ft0 + ft1);
    add = __shfl(add, 0, 16);          // broadcast within the 16-lane group

    const float4* m4 = (const float4*)(memory + (size_t)g * F);
    float4*       o4 = (float4*)(out + (size_t)g * F);
#pragma unroll
    for (int c = l; c < F / 4; c += 16) {   // 25 float4 per row
        float4 m = m4[c];
        float4 o;
        o.x = m.x + add; o.y = m.y + add;
        o.z = m.z + add; o.w = m.w + add;
        o4[c] = o;
    }
}

extern "C" void kernel_launch(void* const* d_in, const int* in_sizes, int n_in,
                              void* d_out, int out_size, void* d_ws, size_t ws_size,
                              hipStream_t stream)
{
    const float* memory     = (const float*)d_in[0];
    const float* node_ts    = (const float*)d_in[1];
    const float* edge_raw   = (const float*)d_in[2];
    const float* edge_ts    = (const float*)d_in[3];
    const float* time_w     = (const float*)d_in[4];
    const float* time_b     = (const float*)d_in[5];
    const float* fc_node_w  = (const float*)d_in[6];
    const float* fc_node_b  = (const float*)d_in[7];
    const float* fc_edge_w  = (const float*)d_in[8];
    const float* fc_edge_b  = (const float*)d_in[9];
    const float* attn_l     = (const float*)d_in[10];
    const float* attn_r     = (const float*)d_in[11];
    const float* attn_e     = (const float*)d_in[12];
    const int*   src        = (const int*)d_in[13];
    const int*   dst        = (const int*)d_in[14];
    float*       out        = (float*)d_out;

    const int N = in_sizes[1];   // node_ts
    const int E = in_sizes[3];   // edge_ts

    // workspace layout (floats):
    // [0,400)        w_node (100 x float4)
    // [400,800)      w_edge (200 x float2)
    // [800,816)      bias
    // [816,+4N)      el_er  (N x float4)
    // [+N)           addbuf slot (unused; kept for layout stability)
    // ints: cnt[N], offs[N], cursor[N], bsum[256]
    // bucket: E x float4 (16B-aligned)
    float* ws = (float*)d_ws;
    float4* w_node  = (float4*)ws;
    float2* w_edge  = (float2*)(ws + 400);
    float*  bias    = ws + 800;
    float4* el_er   = (float4*)(ws + 816);
    int*    cnt     = (int*)(ws + 816 + 5 * (size_t)N);
    int*    offs    = cnt + N;
    int*    cursor  = offs + N;
    int*    bsum    = cursor + N;
    size_t  boff    = 816 + 8 * (size_t)N + 256;
    boff            = (boff + 3) & ~(size_t)3;
    float4* bucket  = (float4*)(ws + boff);

    const int nb = (N + 255) / 256;   // scan blocks (<= 256 required)

    {
        int wblocks = (3 * F + 6 + 3) / 4;          // wave work
        int blocks  = (nb > wblocks) ? nb : wblocks; // breadth for cnt zeroing
        precompute_kernel<<<blocks, 256, 0, stream>>>(
            fc_node_w, fc_node_b, fc_edge_w, fc_edge_b,
            attn_l, attn_r, attn_e, w_node, w_edge, bias, cnt, N);
    }
    {
        int nodeBlocks  = (N + 3) / 4;
        int countBlocks = (E + 255) / 256;
        node_count_kernel<<<nodeBlocks + countBlocks, 256, 0, stream>>>(
            memory, w_node, bias, el_er, dst, cnt, N, E, nodeBlocks);
    }
    scan1_kernel<<<nb, 256, 0, stream>>>(cnt, offs, bsum, N);
    scan23_kernel<<<nb, 256, 0, stream>>>(offs, bsum, cursor, N, nb);
    {
        int blocks = (E + EPB - 1) / EPB;
        edge_gemv_kernel<<<blocks, 256, 0, stream>>>(
            edge_raw, edge_ts, node_ts, src, dst, time_w, time_b,
            w_edge, bias, el_er, cursor, bucket, E);
    }
    {
        int blocks = (N + 15) / 16;
        reduce_out_kernel<<<blocks, 256, 0, stream>>>(
            bucket, offs, cnt, memory, out, N);
    }
}